// Round 1
// baseline (1825.853 us; speedup 1.0000x reference)
//
#include <hip/hip_runtime.h>
#include <math.h>

#define N_ATOMS 50000
#define N_PAIRS 1600000
#define NF 128
#define NRBF 20

typedef _Float16 half8 __attribute__((ext_vector_type(8)));
typedef float floatx4 __attribute__((ext_vector_type(4)));

__device__ __forceinline__ float sspf(float x) {
    float t = __expf(-fabsf(x));
    return fmaxf(x, 0.0f) + __logf(1.0f + t) - 0.69314718055994530942f;
}

// Swizzled LDS layout for a [128 rows x 128 fp16] matrix (256 B rows).
// 16B group k8 of row r lives at XOR'd position (k8 ^ (r & 15)).
__device__ __forceinline__ int swz16(int row, int k8) {
    return row * 256 + ((k8 ^ (row & 15)) << 4);
}

// ---------------- prep: pre-convert W matrices to fp16, transposed+swizzled
// images (exact LDS byte image), and zero the histogram counters. ----------------
__global__ __launch_bounds__(256) void prep_kernel(
    const float* __restrict__ W_in, const float* __restrict__ Wf2,
    const float* __restrict__ Wo1, const float* __restrict__ Wo2,
    _Float16* __restrict__ Wimg, int* __restrict__ woffs)
{
    const int b = blockIdx.x;   // 0..3
    const float* W = (b == 0) ? W_in : (b == 1) ? Wf2 : (b == 2) ? Wo1 : Wo2;
    char* img = (char*)(Wimg + b * 16384);
    for (int i = threadIdx.x; i < 16384; i += 256) {
        int c = i & 127, k = i >> 7;                 // coalesced in c
        *(_Float16*)(img + swz16(c, k >> 3) + ((k & 7) << 1)) = (_Float16)W[k * 128 + c];
    }
    for (int i = b * 256 + threadIdx.x; i < N_ATOMS; i += 1024) woffs[i] = 0;
}

// ---------------- counting sort of edges by idx_i ----------------
__global__ __launch_bounds__(256) void hist_kernel(
    const int* __restrict__ idx_i, int* __restrict__ cnt)
{
    for (int e = blockIdx.x * 256 + threadIdx.x; e < N_PAIRS; e += gridDim.x * 256)
        atomicAdd(&cnt[idx_i[e]], 1);
}

// single-block exclusive scan over 50000 counts (in woffs); writes offs[0..50000]
// and resets woffs[a] = start offset (scatter bumps it).
__global__ __launch_bounds__(1024) void scan_kernel(
    int* __restrict__ woffs, int* __restrict__ offs)
{
    __shared__ int sc[1024];
    const int t = threadIdx.x;
    const int CH = 49;                                // 1024*49 >= 50000
    int lo = t * CH, hi = lo + CH;
    if (lo > N_ATOMS) lo = N_ATOMS;
    if (hi > N_ATOMS) hi = N_ATOMS;
    int s = 0;
    for (int i = lo; i < hi; ++i) s += woffs[i];
    sc[t] = s;
    __syncthreads();
    for (int off = 1; off < 1024; off <<= 1) {
        int v = (t >= off) ? sc[t - off] : 0;
        __syncthreads();
        sc[t] += v;
        __syncthreads();
    }
    int run = sc[t] - s;                              // exclusive prefix
    for (int i = lo; i < hi; ++i) {
        int c = woffs[i];
        offs[i] = run;
        woffs[i] = run;
        run += c;
    }
    if (hi == N_ATOMS && lo < N_ATOMS) offs[N_ATOMS] = run;
}

__global__ __launch_bounds__(256) void scatter_kernel(
    const int* __restrict__ idx_i, int* __restrict__ woffs, int* __restrict__ eid_s)
{
    for (int e = blockIdx.x * 256 + threadIdx.x; e < N_PAIRS; e += gridDim.x * 256) {
        int pos = atomicAdd(&woffs[idx_i[e]], 1);
        eid_s[pos] = e;
    }
}

// ---------------- shared staging: straight 32KB copy of pre-swizzled image ----------------
template<int NTHR>
__device__ __forceinline__ void stage_img(const _Float16* __restrict__ img, char* dst, int t) {
    const float4* s = (const float4*)img;
    float4* d = (float4*)dst;
    for (int i = t; i < 2048; i += NTHR) d[i] = s[i];
}

// ---------------- generic 128x128 MFMA gemm: out = postop(A @ W + bias) ----------------
template<typename TIN, typename TOUT, bool SSP_OUT>
__global__ __launch_bounds__(256) void gemm_mfma_kernel(
    const TIN* __restrict__ A, const _Float16* __restrict__ Wimg,
    const float* __restrict__ bias, TOUT* __restrict__ out, int M)
{
    __shared__ char sW[32768];
    const int t = threadIdx.x;
    const int w = t >> 6, lane = t & 63, m = lane & 15, q = lane >> 4;

    stage_img<256>(Wimg, sW, t);
    float bv[8];
    #pragma unroll
    for (int g = 0; g < 8; ++g) bv[g] = bias[g * 16 + m];
    __syncthreads();

    const floatx4 zero4 = {0.f, 0.f, 0.f, 0.f};
    const int ntiles = (M + 63) >> 6;
    for (int tile = blockIdx.x; tile < ntiles; tile += gridDim.x) {
        const int arow = tile * 64 + w * 16 + m;
        half8 a[4];
        if (arow < M) {
            const TIN* ap = A + (size_t)arow * 128;
            #pragma unroll
            for (int s = 0; s < 4; ++s) {
                if (sizeof(TIN) == 2) {
                    a[s] = *(const half8*)(ap + s * 32 + q * 8);
                } else {
                    float4 u0 = *(const float4*)((const float*)ap + s * 32 + q * 8);
                    float4 u1 = *(const float4*)((const float*)ap + s * 32 + q * 8 + 4);
                    a[s][0] = (_Float16)u0.x; a[s][1] = (_Float16)u0.y;
                    a[s][2] = (_Float16)u0.z; a[s][3] = (_Float16)u0.w;
                    a[s][4] = (_Float16)u1.x; a[s][5] = (_Float16)u1.y;
                    a[s][6] = (_Float16)u1.z; a[s][7] = (_Float16)u1.w;
                }
            }
        } else {
            #pragma unroll
            for (int s = 0; s < 4; ++s) a[s] = (half8){};
        }
        floatx4 acc[8];
        #pragma unroll
        for (int g = 0; g < 8; ++g) {
            floatx4 c = zero4;
            #pragma unroll
            for (int s = 0; s < 4; ++s) {
                half8 b = *(const half8*)(sW + swz16(g * 16 + m, 4 * s + q));
                c = __builtin_amdgcn_mfma_f32_16x16x32_f16(a[s], b, c, 0, 0, 0);
            }
            acc[g] = c;
        }
        #pragma unroll
        for (int r = 0; r < 4; ++r) {
            const int grow = tile * 64 + w * 16 + q * 4 + r;
            if (grow < M) {
                TOUT* op = out + (size_t)grow * 128;
                #pragma unroll
                for (int g = 0; g < 8; ++g) {
                    float v = acc[g][r] + bv[g];
                    if (SSP_OUT) v = sspf(v);
                    op[g * 16 + m] = (TOUT)v;
                }
            }
        }
    }
}

// ---------------- edge kernel (sorted): wave owns whole atoms; edges come from
// the sorted list; per-atom register accumulation; ONE plain store per agg row.
// Zero atomics. ----------------
__global__ __launch_bounds__(256, 3) void edge_kernel(
    const float* __restrict__ f_ij, const float* __restrict__ rcut,
    const float* __restrict__ Wf1, const float* __restrict__ bf1,
    const _Float16* __restrict__ Wf2img, const float* __restrict__ bf2,
    const int* __restrict__ idx_j,
    const int* __restrict__ offs, const int* __restrict__ eid_s,
    const _Float16* __restrict__ h, float* __restrict__ agg)
{
    __shared__ char sW2[32768];
    __shared__ char sS[4][4096];   // wave-private 16-row slabs
    const int t = threadIdx.x;
    const int w = t >> 6, lane = t & 63, m = lane & 15, q = lane >> 4;

    stage_img<256>(Wf2img, sW2, t);
    half8 bW1[8];
    #pragma unroll
    for (int g = 0; g < 8; ++g) {
        #pragma unroll
        for (int j = 0; j < 8; ++j) {
            int k = q * 8 + j;
            bW1[g][j] = (k < NRBF) ? (_Float16)Wf1[k * 128 + g * 16 + m] : (_Float16)0.0f;
        }
    }
    float bf1r[8], bf2r[8];
    #pragma unroll
    for (int g = 0; g < 8; ++g) { bf1r[g] = bf1[g * 16 + m]; bf2r[g] = bf2[g * 16 + m]; }
    __syncthreads();   // sW2 ready; no barriers after this

    char* mySS = sS[w];
    const floatx4 zero4 = {0.f, 0.f, 0.f, 0.f};
    const float4 fz = {0.f, 0.f, 0.f, 0.f};
    const int wid = blockIdx.x * 4 + w;
    const int nw = gridDim.x * 4;

    for (int a = wid; a < N_ATOMS; a += nw) {
        const int start = offs[a], end = offs[a + 1];
        float racc[8];
        #pragma unroll
        for (int g = 0; g < 8; ++g) racc[g] = 0.f;

        for (int base = start; base < end; base += 16) {
            // A-row gather: f of sorted edge base+m (clamped; garbage rows masked by rc=0)
            int em = base + m; if (em >= end) em = end - 1;
            const int eidm = eid_s[em];
            const float* fb = f_ij + (size_t)eidm * NRBF + q * 8;
            float4 f0 = fz, f1 = fz;
            if (q < 2)       { f0 = *(const float4*)fb; f1 = *(const float4*)(fb + 4); }
            else if (q == 2) { f0 = *(const float4*)fb; }

            // epilogue edges for this lane's q-group: slots base+q*4+r
            int jj[4]; float rc[4];
            #pragma unroll
            for (int r = 0; r < 4; ++r) {
                int s = base + q * 4 + r;
                int vs = (s < end) ? s : end - 1;
                int e = eid_s[vs];
                jj[r] = idx_j[e];
                rc[r] = (s < end) ? rcut[e] : 0.f;   // masks padded slots
            }

            // h gathers (consumed after mm2)
            _Float16 hv[4][8];
            #pragma unroll
            for (int r = 0; r < 4; ++r) {
                const _Float16* hp = h + (size_t)jj[r] * NF;
                #pragma unroll
                for (int g = 0; g < 8; ++g) hv[r][g] = hp[g * 16 + m];
            }

            // mm1: s = f @ Wf1
            half8 a1;
            a1[0] = (_Float16)f0.x; a1[1] = (_Float16)f0.y;
            a1[2] = (_Float16)f0.z; a1[3] = (_Float16)f0.w;
            a1[4] = (_Float16)f1.x; a1[5] = (_Float16)f1.y;
            a1[6] = (_Float16)f1.z; a1[7] = (_Float16)f1.w;
            floatx4 c1[8];
            #pragma unroll
            for (int g = 0; g < 8; ++g)
                c1[g] = __builtin_amdgcn_mfma_f32_16x16x32_f16(a1, bW1[g], zero4, 0, 0, 0);

            // ssp + write to private slab (fp16, swizzled)
            #pragma unroll
            for (int g = 0; g < 8; ++g) {
                #pragma unroll
                for (int r = 0; r < 4; ++r) {
                    float v = sspf(c1[g][r] + bf1r[g]);
                    *(_Float16*)(mySS + swz16(q * 4 + r, 2 * g + (m >> 3)) + ((m & 7) << 1)) =
                        (_Float16)v;
                }
            }

            // read back A-frags (same-wave rows; lgkmcnt orders, no barrier)
            half8 a2[4];
            #pragma unroll
            for (int s = 0; s < 4; ++s)
                a2[s] = *(const half8*)(mySS + swz16(m, 4 * s + q));

            // mm2 + fused accumulate into per-atom register sums
            #pragma unroll
            for (int g = 0; g < 8; ++g) {
                floatx4 c = zero4;
                #pragma unroll
                for (int s = 0; s < 4; ++s) {
                    half8 b = *(const half8*)(sW2 + swz16(g * 16 + m, 4 * s + q));
                    c = __builtin_amdgcn_mfma_f32_16x16x32_f16(a2[s], b, c, 0, 0, 0);
                }
                #pragma unroll
                for (int r = 0; r < 4; ++r)
                    racc[g] += ((c[r] + bf2r[g]) * rc[r]) * (float)hv[r][g];
            }
        }

        // cross-q reduce (lanes l, l^16, l^32, l^48 hold partials of same column) + store
        #pragma unroll
        for (int g = 0; g < 8; ++g) {
            float v = racc[g];
            v += __shfl_xor(v, 16, 64);
            v += __shfl_xor(v, 32, 64);
            if (q == 0) agg[(size_t)a * NF + g * 16 + m] = v;
        }
    }
}

extern "C" void kernel_launch(void* const* d_in, const int* in_sizes, int n_in,
                              void* d_out, int out_size, void* d_ws, size_t ws_size,
                              hipStream_t stream) {
    const float* x     = (const float*)d_in[0];
    const float* f_ij  = (const float*)d_in[1];
    const float* rcutp = (const float*)d_in[2];
    const float* W_in  = (const float*)d_in[3];
    const float* b_in  = (const float*)d_in[4];
    const float* Wf1   = (const float*)d_in[5];
    const float* bf1   = (const float*)d_in[6];
    const float* Wf2   = (const float*)d_in[7];
    const float* bf2   = (const float*)d_in[8];
    const float* Wo1   = (const float*)d_in[9];
    const float* bo1   = (const float*)d_in[10];
    const float* Wo2   = (const float*)d_in[11];
    const float* bo2   = (const float*)d_in[12];
    const int* idx_i   = (const int*)d_in[13];
    const int* idx_j   = (const int*)d_in[14];
    float* out = (float*)d_out;

    // workspace layout (all 16B-aligned)
    char* ws = (char*)d_ws;
    float*    agg   = (float*)ws;                              // 25,600,000 B
    _Float16* h     = (_Float16*)(ws + 25600000);              // 12,800,000 B
    int*      eid_s = (int*)(ws + 38400000);                   //  6,400,000 B
    int*      offs  = (int*)(ws + 44800000);                   //    200,004 B (+pad)
    int*      woffs = (int*)(ws + 45000016);                   //    200,000 B
    _Float16* Wimg  = (_Float16*)(ws + 45200016);              //    131,072 B
    _Float16* tmp   = h;                                       // h dead after edge

    // 0) pre-convert W images (Win, Wf2, Wo1, Wo2) + zero histogram
    prep_kernel<<<dim3(4), 256, 0, stream>>>(W_in, Wf2, Wo1, Wo2, Wimg, woffs);
    // 1) h = x@W_in+b (fp16 out)
    gemm_mfma_kernel<float, _Float16, false>
        <<<dim3(782), 256, 0, stream>>>(x, Wimg, b_in, h, N_ATOMS);
    // 2) counting sort of edges by idx_i
    hist_kernel<<<dim3(1024), 256, 0, stream>>>(idx_i, woffs);
    scan_kernel<<<dim3(1), 1024, 0, stream>>>(woffs, offs);
    scatter_kernel<<<dim3(1024), 256, 0, stream>>>(idx_i, woffs, eid_s);
    // 3) edge pass: sorted, register-accumulated, atomic-free
    edge_kernel<<<dim3(768), 256, 0, stream>>>(f_ij, rcutp, Wf1, bf1, Wimg + 16384, bf2,
                                               idx_j, offs, eid_s, h, agg);
    // 4) out = ssp(agg@Wo1+bo1)@Wo2+bo2
    gemm_mfma_kernel<float, _Float16, true>
        <<<dim3(782), 256, 0, stream>>>(agg, Wimg + 32768, bo1, tmp, N_ATOMS);
    gemm_mfma_kernel<_Float16, float, false>
        <<<dim3(782), 256, 0, stream>>>(tmp, Wimg + 49152, bo2, out, N_ATOMS);
}

// Round 3
// 913.726 us; speedup vs baseline: 1.9982x; 1.9982x over previous
//
#include <hip/hip_runtime.h>
#include <math.h>

#define N_ATOMS 50000
#define N_PAIRS 1600000
#define NF 128
#define NRBF 20
#define PADCAP 2200000              // padded edge-slot capacity (actual ~1.98M)
#define NTILE_CAP (PADCAP / 16)

typedef _Float16 half8 __attribute__((ext_vector_type(8)));
typedef float floatx4 __attribute__((ext_vector_type(4)));
typedef unsigned long long u64;
typedef unsigned short u16;

__device__ __forceinline__ float sspf(float x) {
    float t = __expf(-fabsf(x));
    return fmaxf(x, 0.0f) + __logf(1.0f + t) - 0.69314718055994530942f;
}

// Swizzled LDS layout for a [128 rows x 128 fp16] matrix (256 B rows).
__device__ __forceinline__ int swz16(int row, int k8) {
    return row * 256 + ((k8 ^ (row & 15)) << 4);
}

// ---------------- prep: W fp16 transposed+swizzled images + zero histogram ----------------
__global__ __launch_bounds__(256) void prep_kernel(
    const float* __restrict__ W_in, const float* __restrict__ Wf2,
    const float* __restrict__ Wo1, const float* __restrict__ Wo2,
    _Float16* __restrict__ Wimg, int* __restrict__ woffs)
{
    const int b = blockIdx.x;   // 0..3
    const float* W = (b == 0) ? W_in : (b == 1) ? Wf2 : (b == 2) ? Wo1 : Wo2;
    char* img = (char*)(Wimg + b * 16384);
    for (int i = threadIdx.x; i < 16384; i += 256) {
        int c = i & 127, k = i >> 7;
        *(_Float16*)(img + swz16(c, k >> 3) + ((k & 7) << 1)) = (_Float16)W[k * 128 + c];
    }
    for (int i = b * 256 + threadIdx.x; i < N_ATOMS; i += 1024) woffs[i] = 0;
}

// ---------------- counting sort: histogram ----------------
__global__ __launch_bounds__(256) void hist_kernel(
    const int* __restrict__ idx_i, int* __restrict__ cnt)
{
    for (int e = blockIdx.x * 256 + threadIdx.x; e < N_PAIRS; e += gridDim.x * 256)
        atomicAdd(&cnt[idx_i[e]], 1);
}

// single-block scan over per-atom TILE counts (ceil(cnt/16)); emits per-tile
// descriptors (atom<<5 | valid-count), padded slot starts in woffs, and NT in meta[0].
__global__ __launch_bounds__(1024) void scan_kernel(
    int* __restrict__ woffs, int* __restrict__ desc, int* __restrict__ meta)
{
    __shared__ int sc[1024];
    const int t = threadIdx.x;
    const int CH = 49;                                // 1024*49 >= 50000
    int lo = t * CH, hi = lo + CH;
    if (lo > N_ATOMS) lo = N_ATOMS;
    if (hi > N_ATOMS) hi = N_ATOMS;
    int s = 0;
    for (int i = lo; i < hi; ++i) s += (woffs[i] + 15) >> 4;
    sc[t] = s;
    __syncthreads();
    for (int off = 1; off < 1024; off <<= 1) {
        int v = (t >= off) ? sc[t - off] : 0;
        __syncthreads();
        sc[t] += v;
        __syncthreads();
    }
    int tb = sc[t] - s;                               // exclusive tile prefix
    for (int i = lo; i < hi; ++i) {
        int c = woffs[i];
        int nt = (c + 15) >> 4;
        woffs[i] = tb * 16;                           // padded slot start (scatter bumps)
        for (int k = 0; k < nt; ++k) {
            int nv = c - k * 16; if (nv > 16) nv = 16;
            if (tb + k < NTILE_CAP) desc[tb + k] = (i << 5) | nv;
        }
        tb += nt;
    }
    if (t == 1023) { int NT = sc[1023]; meta[0] = NT < NTILE_CAP ? NT : NTILE_CAP; }
}

// ---------------- scatter-permute: stream edges, write fp16 f-row (20 halves),
// rcut (f32) and idx_j (u16) at the sorted padded position ----------------
__global__ __launch_bounds__(256) void scatter_permute_kernel(
    const float* __restrict__ f_ij, const float* __restrict__ rcut,
    const int* __restrict__ idx_i, const int* __restrict__ idx_j,
    int* __restrict__ woffs, u16* __restrict__ f_s,
    float* __restrict__ rc_s, u16* __restrict__ j_s)
{
    for (int e = blockIdx.x * 256 + threadIdx.x; e < N_PAIRS; e += gridDim.x * 256) {
        int pos = atomicAdd(&woffs[idx_i[e]], 1);
        if (pos >= PADCAP) continue;                  // impossible by construction; safety
        const float4* fr = (const float4*)(f_ij + (size_t)e * NRBF);
        u16* dst = f_s + (size_t)pos * 20;
        #pragma unroll
        for (int v = 0; v < 5; ++v) {
            float4 fv = fr[v];
            union { _Float16 hf; u16 b; } c0, c1, c2, c3;
            c0.hf = (_Float16)fv.x; c1.hf = (_Float16)fv.y;
            c2.hf = (_Float16)fv.z; c3.hf = (_Float16)fv.w;
            ushort4 o; o.x = c0.b; o.y = c1.b; o.z = c2.b; o.w = c3.b;
            *(ushort4*)(dst + v * 4) = o;
        }
        rc_s[pos] = rcut[e];
        j_s[pos] = (u16)idx_j[e];
    }
}

// ---------------- staging: straight 32KB copy of pre-swizzled image ----------------
template<int NTHR>
__device__ __forceinline__ void stage_img(const _Float16* __restrict__ img, char* dst, int t) {
    const float4* s = (const float4*)img;
    float4* d = (float4*)dst;
    for (int i = t; i < 2048; i += NTHR) d[i] = s[i];
}

// ---------------- generic 128x128 MFMA gemm: out = postop(A @ W + bias) ----------------
template<typename TIN, typename TOUT, bool SSP_OUT, bool ZERO>
__global__ __launch_bounds__(256) void gemm_mfma_kernel(
    const TIN* __restrict__ A, const _Float16* __restrict__ Wimg,
    const float* __restrict__ bias, TOUT* __restrict__ out, int M,
    float* __restrict__ zbuf, int zcount4)
{
    __shared__ char sW[32768];
    const int t = threadIdx.x;
    const int w = t >> 6, lane = t & 63, m = lane & 15, q = lane >> 4;

    if (ZERO) {
        float4 z = {0.f, 0.f, 0.f, 0.f};
        for (int i = blockIdx.x * 256 + t; i < zcount4; i += gridDim.x * 256)
            ((float4*)zbuf)[i] = z;
    }
    stage_img<256>(Wimg, sW, t);
    float bv[8];
    #pragma unroll
    for (int g = 0; g < 8; ++g) bv[g] = bias[g * 16 + m];
    __syncthreads();

    const floatx4 zero4 = {0.f, 0.f, 0.f, 0.f};
    const int ntiles = (M + 63) >> 6;
    for (int tile = blockIdx.x; tile < ntiles; tile += gridDim.x) {
        const int arow = tile * 64 + w * 16 + m;
        half8 a[4];
        if (arow < M) {
            const TIN* ap = A + (size_t)arow * 128;
            #pragma unroll
            for (int s = 0; s < 4; ++s) {
                if (sizeof(TIN) == 2) {
                    a[s] = *(const half8*)(ap + s * 32 + q * 8);
                } else {
                    float4 u0 = *(const float4*)((const float*)ap + s * 32 + q * 8);
                    float4 u1 = *(const float4*)((const float*)ap + s * 32 + q * 8 + 4);
                    a[s][0] = (_Float16)u0.x; a[s][1] = (_Float16)u0.y;
                    a[s][2] = (_Float16)u0.z; a[s][3] = (_Float16)u0.w;
                    a[s][4] = (_Float16)u1.x; a[s][5] = (_Float16)u1.y;
                    a[s][6] = (_Float16)u1.z; a[s][7] = (_Float16)u1.w;
                }
            }
        } else {
            #pragma unroll
            for (int s = 0; s < 4; ++s) a[s] = (half8){};
        }
        floatx4 acc[8];
        #pragma unroll
        for (int g = 0; g < 8; ++g) {
            floatx4 c = zero4;
            #pragma unroll
            for (int s = 0; s < 4; ++s) {
                half8 b = *(const half8*)(sW + swz16(g * 16 + m, 4 * s + q));
                c = __builtin_amdgcn_mfma_f32_16x16x32_f16(a[s], b, c, 0, 0, 0);
            }
            acc[g] = c;
        }
        #pragma unroll
        for (int r = 0; r < 4; ++r) {
            const int grow = tile * 64 + w * 16 + q * 4 + r;
            if (grow < M) {
                TOUT* op = out + (size_t)grow * 128;
                #pragma unroll
                for (int g = 0; g < 8; ++g) {
                    float v = acc[g][r] + bv[g];
                    if (SSP_OUT) v = sspf(v);
                    op[g * 16 + m] = (TOUT)v;
                }
            }
        }
    }
}

// ---------------- edge kernel (sorted+permuted): waves own CONTIGUOUS tile ranges;
// sequential fp16 f-reads; register accumulation across an atom's tiles; one
// atomic row-flush per (wave,atom). ----------------
__global__ __launch_bounds__(256) void edge_kernel(
    const u64* __restrict__ f_s, const float* __restrict__ rc_s,
    const u16* __restrict__ j_s, const int* __restrict__ desc,
    const int* __restrict__ meta,
    const float* __restrict__ Wf1, const float* __restrict__ bf1,
    const _Float16* __restrict__ Wf2img, const float* __restrict__ bf2,
    const _Float16* __restrict__ h, float* __restrict__ agg)
{
    __shared__ char sW2[32768];
    __shared__ char sS[4][4096];   // wave-private 16-row slabs
    const int t = threadIdx.x;
    const int w = t >> 6, lane = t & 63, m = lane & 15, q = lane >> 4;

    stage_img<256>(Wf2img, sW2, t);
    half8 bW1[8];
    #pragma unroll
    for (int g = 0; g < 8; ++g) {
        #pragma unroll
        for (int j = 0; j < 8; ++j) {
            int k = q * 8 + j;
            bW1[g][j] = (k < NRBF) ? (_Float16)Wf1[k * 128 + g * 16 + m] : (_Float16)0.0f;
        }
    }
    float bf1r[8], bf2r[8];
    #pragma unroll
    for (int g = 0; g < 8; ++g) { bf1r[g] = bf1[g * 16 + m]; bf2r[g] = bf2[g * 16 + m]; }
    __syncthreads();   // no barriers after this

    char* mySS = sS[w];
    const floatx4 zero4 = {0.f, 0.f, 0.f, 0.f};
    const int NT = meta[0];
    const int nw = gridDim.x * 4;
    const int wid = blockIdx.x * 4 + w;
    const int T = (NT + nw - 1) / nw;
    int t0 = wid * T, t1 = t0 + T;
    if (t1 > NT) t1 = NT;
    if (t0 >= t1) return;

    auto loadtile = [&](int tt, int& d_, u64& x0_, u64& x1_, int* jjv, float4& rcv) {
        d_ = desc[tt];
        const u64* fr = f_s + (size_t)(tt * 16 + m) * 5;
        u64 x0 = 0, x1 = 0;
        if (q < 2)       { x0 = fr[2 * q]; x1 = fr[2 * q + 1]; }
        else if (q == 2) { x0 = fr[4]; }
        x0_ = x0; x1_ = x1;
        ushort4 jv = *(const ushort4*)(j_s + tt * 16 + q * 4);
        jjv[0] = jv.x; jjv[1] = jv.y; jjv[2] = jv.z; jjv[3] = jv.w;
        rcv = *(const float4*)(rc_s + tt * 16 + q * 4);
    };

    int d; u64 u0, u1; int jj[4]; float4 rc4;
    loadtile(t0, d, u0, u1, jj, rc4);

    float racc[8];
    #pragma unroll
    for (int g = 0; g < 8; ++g) racc[g] = 0.f;

    for (int tt = t0; tt < t1; ++tt) {
        const int nv = d & 31;
        const int atom = d >> 5;

        // masked per-slot meta for current tile
        float rcarr[4] = {rc4.x, rc4.y, rc4.z, rc4.w};
        float rc[4]; int jm[4];
        #pragma unroll
        for (int r = 0; r < 4; ++r) {
            int sidx = q * 4 + r;
            bool ok = sidx < nv;
            jm[r] = ok ? jj[r] : 0;
            rc[r] = ok ? rcarr[r] : 0.f;
        }
        // h gathers (consumed after mm2)
        _Float16 hv[4][8];
        #pragma unroll
        for (int r = 0; r < 4; ++r) {
            const _Float16* hp = h + (size_t)jm[r] * NF;
            #pragma unroll
            for (int g = 0; g < 8; ++g) hv[r][g] = hp[g * 16 + m];
        }
        // prefetch next tile (sequential!)
        int nd = 0; u64 nu0 = 0, nu1 = 0; int njj[4] = {0, 0, 0, 0};
        float4 nrc4 = {0.f, 0.f, 0.f, 0.f};
        if (tt + 1 < t1) loadtile(tt + 1, nd, nu0, nu1, njj, nrc4);

        // a1 from prefetched fp16 row (zero padded rows to avoid NaN*0)
        union { u64 u[2]; half8 v; } cv;
        cv.u[0] = u0; cv.u[1] = u1;
        half8 a1 = cv.v;
        if (m >= nv) a1 = (half8){};

        // mm1: s = f @ Wf1
        floatx4 c1[8];
        #pragma unroll
        for (int g = 0; g < 8; ++g)
            c1[g] = __builtin_amdgcn_mfma_f32_16x16x32_f16(a1, bW1[g], zero4, 0, 0, 0);

        // ssp + write to private slab (fp16, swizzled)
        #pragma unroll
        for (int g = 0; g < 8; ++g) {
            #pragma unroll
            for (int r = 0; r < 4; ++r) {
                float v = sspf(c1[g][r] + bf1r[g]);
                *(_Float16*)(mySS + swz16(q * 4 + r, 2 * g + (m >> 3)) + ((m & 7) << 1)) =
                    (_Float16)v;
            }
        }
        // read back A-frags (same-wave rows; lgkmcnt orders, no barrier)
        half8 a2[4];
        #pragma unroll
        for (int s = 0; s < 4; ++s)
            a2[s] = *(const half8*)(mySS + swz16(m, 4 * s + q));

        // mm2 + fused accumulate into per-atom register sums
        #pragma unroll
        for (int g = 0; g < 8; ++g) {
            floatx4 c = zero4;
            #pragma unroll
            for (int s = 0; s < 4; ++s) {
                half8 b = *(const half8*)(sW2 + swz16(g * 16 + m, 4 * s + q));
                c = __builtin_amdgcn_mfma_f32_16x16x32_f16(a2[s], b, c, 0, 0, 0);
            }
            #pragma unroll
            for (int r = 0; r < 4; ++r)
                racc[g] += ((c[r] + bf2r[g]) * rc[r]) * (float)hv[r][g];
        }

        // flush when the atom run ends (next tile is a different atom, or range end)
        bool last = (tt + 1 >= t1);
        if (last || (nd >> 5) != atom) {
            #pragma unroll
            for (int g = 0; g < 8; ++g) {
                float v = racc[g];
                v += __shfl_xor(v, 16, 64);
                v += __shfl_xor(v, 32, 64);
                if (q == 0) atomicAdd(&agg[(size_t)atom * NF + g * 16 + m], v);
                racc[g] = 0.f;
            }
        }
        d = nd; u0 = nu0; u1 = nu1;
        jj[0] = njj[0]; jj[1] = njj[1]; jj[2] = njj[2]; jj[3] = njj[3];
        rc4 = nrc4;
    }
}

// ---------------- fallback edge kernel (round-0, atomic-per-edge) for small ws ----------------
__global__ __launch_bounds__(256) void edge_atomic_kernel(
    const float* __restrict__ f_ij, const float* __restrict__ rcut,
    const float* __restrict__ Wf1, const float* __restrict__ bf1,
    const _Float16* __restrict__ Wf2img, const float* __restrict__ bf2,
    const int* __restrict__ idx_i, const int* __restrict__ idx_j,
    const _Float16* __restrict__ h, float* __restrict__ agg)
{
    __shared__ char sW2[32768];
    __shared__ char sS[4][4096];
    const int NTILES = N_PAIRS / 64;
    const int t = threadIdx.x;
    const int w = t >> 6, lane = t & 63, m = lane & 15, q = lane >> 4;

    stage_img<256>(Wf2img, sW2, t);
    half8 bW1[8];
    #pragma unroll
    for (int g = 0; g < 8; ++g) {
        #pragma unroll
        for (int j = 0; j < 8; ++j) {
            int k = q * 8 + j;
            bW1[g][j] = (k < NRBF) ? (_Float16)Wf1[k * 128 + g * 16 + m] : (_Float16)0.0f;
        }
    }
    float bf1r[8], bf2r[8];
    #pragma unroll
    for (int g = 0; g < 8; ++g) { bf1r[g] = bf1[g * 16 + m]; bf2r[g] = bf2[g * 16 + m]; }
    __syncthreads();

    char* mySS = sS[w];
    const floatx4 zero4 = {0.f, 0.f, 0.f, 0.f};
    const float4 fz = {0.f, 0.f, 0.f, 0.f};
    const int stride = gridDim.x;

    float4 f0 = fz, f1 = fz; int4 jj4;
    {
        int e0 = blockIdx.x * 64 + w * 16;
        const float* fb = f_ij + (size_t)(e0 + m) * NRBF + q * 8;
        if (q < 2)      { f0 = *(const float4*)fb; f1 = *(const float4*)(fb + 4); }
        else if (q == 2){ f0 = *(const float4*)fb; }
        jj4 = *(const int4*)&idx_j[e0 + q * 4];
    }

    for (int tile = blockIdx.x; tile < NTILES; tile += stride) {
        const int e0 = tile * 64 + w * 16;
        int ntile = tile + stride; if (ntile >= NTILES) ntile = tile;

        int jj[4] = {jj4.x, jj4.y, jj4.z, jj4.w};
        _Float16 hv[4][8];
        #pragma unroll
        for (int r = 0; r < 4; ++r) {
            const _Float16* hp = h + (size_t)jj[r] * 128;
            #pragma unroll
            for (int g = 0; g < 8; ++g) hv[r][g] = hp[g * 16 + m];
        }
        int4 ii4 = *(const int4*)&idx_i[e0 + q * 4];
        float4 rc4 = *(const float4*)&rcut[e0 + q * 4];

        half8 a1;
        a1[0]=(_Float16)f0.x; a1[1]=(_Float16)f0.y; a1[2]=(_Float16)f0.z; a1[3]=(_Float16)f0.w;
        a1[4]=(_Float16)f1.x; a1[5]=(_Float16)f1.y; a1[6]=(_Float16)f1.z; a1[7]=(_Float16)f1.w;
        floatx4 c1[8];
        #pragma unroll
        for (int g = 0; g < 8; ++g)
            c1[g] = __builtin_amdgcn_mfma_f32_16x16x32_f16(a1, bW1[g], zero4, 0, 0, 0);

        float4 nf0 = fz, nf1 = fz; int4 njj4;
        {
            int ne0 = ntile * 64 + w * 16;
            const float* fb = f_ij + (size_t)(ne0 + m) * NRBF + q * 8;
            if (q < 2)      { nf0 = *(const float4*)fb; nf1 = *(const float4*)(fb + 4); }
            else if (q == 2){ nf0 = *(const float4*)fb; }
            njj4 = *(const int4*)&idx_j[ne0 + q * 4];
        }

        #pragma unroll
        for (int g = 0; g < 8; ++g) {
            #pragma unroll
            for (int r = 0; r < 4; ++r) {
                float v = sspf(c1[g][r] + bf1r[g]);
                *(_Float16*)(mySS + swz16(q * 4 + r, 2 * g + (m >> 3)) + ((m & 7) << 1)) =
                    (_Float16)v;
            }
        }
        half8 a2[4];
        #pragma unroll
        for (int s = 0; s < 4; ++s)
            a2[s] = *(const half8*)(mySS + swz16(m, 4 * s + q));

        floatx4 acc[8];
        #pragma unroll
        for (int g = 0; g < 8; ++g) {
            floatx4 c = zero4;
            #pragma unroll
            for (int s = 0; s < 4; ++s) {
                half8 b = *(const half8*)(sW2 + swz16(g * 16 + m, 4 * s + q));
                c = __builtin_amdgcn_mfma_f32_16x16x32_f16(a2[s], b, c, 0, 0, 0);
            }
            acc[g] = c;
        }

        int ii[4] = {ii4.x, ii4.y, ii4.z, ii4.w};
        float rc[4] = {rc4.x, rc4.y, rc4.z, rc4.w};
        #pragma unroll
        for (int r = 0; r < 4; ++r) {
            float* arow = agg + (size_t)ii[r] * 128;
            #pragma unroll
            for (int g = 0; g < 8; ++g) {
                float wij = (acc[g][r] + bf2r[g]) * rc[r];
                atomicAdd(&arow[g * 16 + m], (float)hv[r][g] * wij);
            }
        }
        f0 = nf0; f1 = nf1; jj4 = njj4;
    }
}

extern "C" void kernel_launch(void* const* d_in, const int* in_sizes, int n_in,
                              void* d_out, int out_size, void* d_ws, size_t ws_size,
                              hipStream_t stream) {
    const float* x     = (const float*)d_in[0];
    const float* f_ij  = (const float*)d_in[1];
    const float* rcutp = (const float*)d_in[2];
    const float* W_in  = (const float*)d_in[3];
    const float* b_in  = (const float*)d_in[4];
    const float* Wf1   = (const float*)d_in[5];
    const float* bf1   = (const float*)d_in[6];
    const float* Wf2   = (const float*)d_in[7];
    const float* bf2   = (const float*)d_in[8];
    const float* Wo1   = (const float*)d_in[9];
    const float* bo1   = (const float*)d_in[10];
    const float* Wo2   = (const float*)d_in[11];
    const float* bo2   = (const float*)d_in[12];
    const int* idx_i   = (const int*)d_in[13];
    const int* idx_j   = (const int*)d_in[14];
    float* out = (float*)d_out;

    // workspace layout (all offsets 16B-aligned)
    char* ws = (char*)d_ws;
    float*     agg   = (float*)ws;                       // 25,600,000
    _Float16*  h     = (_Float16*)(ws + 25600000);       // 12,800,000
    _Float16*  Wimg  = (_Float16*)(ws + 38400000);       //    131,072
    int*       woffs = (int*)(ws + 38531072);            //    200,000
    int*       meta  = (int*)(ws + 38731072);            //         16
    int*       desc  = (int*)(ws + 38731088);            //    550,016
    float*     rc_s  = (float*)(ws + 39281104);          //  8,800,000
    u16*       j_s   = (u16*)(ws + 48081104);            //  4,400,000
    u16*       f_s   = (u16*)(ws + 52481104);            // 88,000,000
    _Float16*  tmp   = h;                                // h dead after edge
    const size_t NEED = 140481104;

    const int zc4 = N_ATOMS * NF / 4;
    prep_kernel<<<dim3(4), 256, 0, stream>>>(W_in, Wf2, Wo1, Wo2, Wimg, woffs);
    // h = x@W_in+b (fp16 out), fused agg zero-fill
    gemm_mfma_kernel<float, _Float16, false, true>
        <<<dim3(782), 256, 0, stream>>>(x, Wimg, b_in, h, N_ATOMS, agg, zc4);

    if (ws_size >= NEED) {
        hist_kernel<<<dim3(1024), 256, 0, stream>>>(idx_i, woffs);
        scan_kernel<<<dim3(1), 1024, 0, stream>>>(woffs, desc, meta);
        scatter_permute_kernel<<<dim3(1024), 256, 0, stream>>>(
            f_ij, rcutp, idx_i, idx_j, woffs, f_s, rc_s, j_s);
        edge_kernel<<<dim3(768), 256, 0, stream>>>(
            (const u64*)f_s, rc_s, j_s, desc, meta,
            Wf1, bf1, Wimg + 16384, bf2, h, agg);
    } else {
        edge_atomic_kernel<<<dim3(768), 256, 0, stream>>>(
            f_ij, rcutp, Wf1, bf1, Wimg + 16384, bf2, idx_i, idx_j, h, agg);
    }

    // out = ssp(agg@Wo1+bo1)@Wo2+bo2
    gemm_mfma_kernel<float, _Float16, true, false>
        <<<dim3(782), 256, 0, stream>>>(agg, Wimg + 32768, bo1, tmp, N_ATOMS, nullptr, 0);
    gemm_mfma_kernel<_Float16, float, false, false>
        <<<dim3(782), 256, 0, stream>>>(tmp, Wimg + 49152, bo2, out, N_ATOMS, nullptr, 0);
}

// Round 4
// 763.410 us; speedup vs baseline: 2.3917x; 1.1969x over previous
//
#include <hip/hip_runtime.h>
#include <math.h>

#define N_ATOMS 50000
#define N_PAIRS 1600000
#define NF 128
#define NRBF 20
#define PADCAP 2050000              // padded edge-slot capacity (actual ~1.985M, 65 sigma)
#define NTILE_CAP (PADCAP / 16)     // 128125
#define NBLK 196                    // ceil(50000/256)

typedef _Float16 half8 __attribute__((ext_vector_type(8)));
typedef float floatx4 __attribute__((ext_vector_type(4)));
typedef unsigned long long u64;
typedef u64 u64x2 __attribute__((ext_vector_type(2)));
typedef unsigned short u16;

__device__ __forceinline__ float sspf(float x) {
    float t = __expf(-fabsf(x));
    return fmaxf(x, 0.0f) + __logf(1.0f + t) - 0.69314718055994530942f;
}

// feature permutation: position i=16g+m holds feature 8m+g (bijection on 0..127)
__device__ __forceinline__ int permf(int i) { return ((i & 15) << 3) | (i >> 4); }

// Swizzled LDS layout for a [128 rows x 128 fp16] matrix (256 B rows).
__device__ __forceinline__ int swz16(int row, int k8) {
    return row * 256 + ((k8 ^ (row & 15)) << 4);
}

// ---------------- prep: W fp16 transposed+swizzled images + zero histogram.
// b==0: W_in std. b==1: Wf2 row+col permuted. b==2: Wo1 std. b==3: Wo2 col-permuted.
__global__ __launch_bounds__(256) void prep_kernel(
    const float* __restrict__ W_in, const float* __restrict__ Wf2,
    const float* __restrict__ Wo1, const float* __restrict__ Wo2,
    _Float16* __restrict__ Wimg, int* __restrict__ woffs)
{
    const int b = blockIdx.x;   // 0..3
    const float* W = (b == 0) ? W_in : (b == 1) ? Wf2 : (b == 2) ? Wo1 : Wo2;
    char* img = (char*)(Wimg + b * 16384);
    for (int i = threadIdx.x; i < 128 * 128; i += 256) {
        int c = i & 127, k = i >> 7;
        float v;
        if (b == 1)      v = W[permf(k) * 128 + permf(c)];
        else if (b == 3) v = W[k * 128 + permf(c)];
        else             v = W[k * 128 + c];
        *(_Float16*)(img + swz16(c, k >> 3) + ((k & 7) << 1)) = (_Float16)v;
    }
    for (int i = b * 256 + threadIdx.x; i < N_ATOMS; i += 1024) woffs[i] = 0;
}

// ---------------- parallel scan pipeline ----------------
// A: per-block sums of tile counts
__global__ __launch_bounds__(256) void scanA_kernel(
    const int* __restrict__ cnt, int* __restrict__ bsum)
{
    __shared__ int red[256];
    const int t = threadIdx.x;
    int i = blockIdx.x * 256 + t;
    int c = (i < N_ATOMS) ? cnt[i] : 0;
    red[t] = (c + 15) >> 4;
    __syncthreads();
    for (int s = 128; s > 0; s >>= 1) {
        if (t < s) red[t] += red[t + s];
        __syncthreads();
    }
    if (t == 0) bsum[blockIdx.x] = red[0];
}

// B: scan the 196 block sums (1 block)
__global__ __launch_bounds__(256) void scanB_kernel(
    const int* __restrict__ bsum, int* __restrict__ bpre, int* __restrict__ meta)
{
    __shared__ int sc[256];
    const int t = threadIdx.x;
    int v = (t < NBLK) ? bsum[t] : 0;
    sc[t] = v;
    __syncthreads();
    for (int off = 1; off < 256; off <<= 1) {
        int x = (t >= off) ? sc[t - off] : 0;
        __syncthreads();
        sc[t] += x;
        __syncthreads();
    }
    if (t < NBLK) bpre[t] = sc[t] - v;          // exclusive block prefix
    if (t == 255) meta[0] = sc[255] < NTILE_CAP ? sc[255] : NTILE_CAP;
}

// C: local scan + write slot starts (woffs) and per-tile descriptors (parallel)
__global__ __launch_bounds__(256) void scanC_kernel(
    int* __restrict__ woffs, const int* __restrict__ bpre,
    int* __restrict__ desc)
{
    __shared__ int sc[256];
    const int t = threadIdx.x;
    int i = blockIdx.x * 256 + t;
    int c = (i < N_ATOMS) ? woffs[i] : 0;
    int nt = (c + 15) >> 4;
    sc[t] = nt;
    __syncthreads();
    for (int off = 1; off < 256; off <<= 1) {
        int x = (t >= off) ? sc[t - off] : 0;
        __syncthreads();
        sc[t] += x;
        __syncthreads();
    }
    int tb = bpre[blockIdx.x] + sc[t] - nt;
    if (i < N_ATOMS) {
        woffs[i] = tb * 16;                      // padded slot start (scatter bumps)
        for (int k = 0; k < nt; ++k) {
            int nv = c - k * 16; if (nv > 16) nv = 16;
            if (tb + k < NTILE_CAP) desc[tb + k] = (i << 5) | nv;
        }
    }
}

// ---------------- scatter-permute: one 48-B record per edge:
// [20 x fp16 f | f32 rcut | u16 idx_j | u16 pad] at slot*48 ----------------
__global__ __launch_bounds__(256) void scatter_kernel(
    const float* __restrict__ f_ij, const float* __restrict__ rcut,
    const int* __restrict__ idx_i, const int* __restrict__ idx_j,
    int* __restrict__ woffs, u64* __restrict__ f_s)
{
    for (int e = blockIdx.x * 256 + threadIdx.x; e < N_PAIRS; e += gridDim.x * 256) {
        int pos = atomicAdd(&woffs[idx_i[e]], 1);
        if (pos >= PADCAP) continue;             // statistically impossible; safety
        const float4* fr = (const float4*)(f_ij + (size_t)e * NRBF);
        u64 qw[6];
        #pragma unroll
        for (int v = 0; v < 5; ++v) {
            float4 fv = fr[v];
            union { u64 u; _Float16 hx[4]; } pk;
            pk.hx[0] = (_Float16)fv.x; pk.hx[1] = (_Float16)fv.y;
            pk.hx[2] = (_Float16)fv.z; pk.hx[3] = (_Float16)fv.w;
            qw[v] = pk.u;
        }
        qw[5] = (u64)__float_as_uint(rcut[e]) | ((u64)(u16)idx_j[e] << 32);
        u64* dst = f_s + (size_t)pos * 6;        // 48B record, 16B aligned
        u64x2 p0 = {qw[0], qw[1]}, p1 = {qw[2], qw[3]}, p2 = {qw[4], qw[5]};
        *(u64x2*)(dst + 0) = p0;
        *(u64x2*)(dst + 2) = p1;
        *(u64x2*)(dst + 4) = p2;
    }
}

// ---------------- staging: straight 32KB copy of pre-swizzled image ----------------
template<int NTHR>
__device__ __forceinline__ void stage_img(const _Float16* __restrict__ img, char* dst, int t) {
    const float4* s = (const float4*)img;
    float4* d = (float4*)dst;
    for (int i = t; i < 2048; i += NTHR) d[i] = s[i];
}

// ---------------- gemm1: h = x @ W_in + b (fp16 out) + fused agg zero + fused hist ----
template<typename TIN, typename TOUT, bool SSP_OUT, bool ZERO, bool HIST>
__global__ __launch_bounds__(256) void gemm_mfma_kernel(
    const TIN* __restrict__ A, const _Float16* __restrict__ Wimg,
    const float* __restrict__ bias, TOUT* __restrict__ out, int M,
    float* __restrict__ zbuf, int zcount4,
    const int* __restrict__ hidx, int* __restrict__ hcnt)
{
    __shared__ char sW[32768];
    const int t = threadIdx.x;
    const int w = t >> 6, lane = t & 63, m = lane & 15, q = lane >> 4;

    if (ZERO) {
        float4 z = {0.f, 0.f, 0.f, 0.f};
        for (int i = blockIdx.x * 256 + t; i < zcount4; i += gridDim.x * 256)
            ((float4*)zbuf)[i] = z;
    }
    if (HIST) {
        for (int e = blockIdx.x * 256 + t; e < N_PAIRS; e += gridDim.x * 256)
            atomicAdd(&hcnt[hidx[e]], 1);
    }
    stage_img<256>(Wimg, sW, t);
    float bv[8];
    #pragma unroll
    for (int g = 0; g < 8; ++g) bv[g] = bias[g * 16 + m];
    __syncthreads();

    const floatx4 zero4 = {0.f, 0.f, 0.f, 0.f};
    const int ntiles = (M + 63) >> 6;
    for (int tile = blockIdx.x; tile < ntiles; tile += gridDim.x) {
        const int arow = tile * 64 + w * 16 + m;
        half8 a[4];
        if (arow < M) {
            const TIN* ap = A + (size_t)arow * 128;
            #pragma unroll
            for (int s = 0; s < 4; ++s) {
                if (sizeof(TIN) == 2) {
                    a[s] = *(const half8*)(ap + s * 32 + q * 8);
                } else {
                    float4 u0 = *(const float4*)((const float*)ap + s * 32 + q * 8);
                    float4 u1 = *(const float4*)((const float*)ap + s * 32 + q * 8 + 4);
                    a[s][0] = (_Float16)u0.x; a[s][1] = (_Float16)u0.y;
                    a[s][2] = (_Float16)u0.z; a[s][3] = (_Float16)u0.w;
                    a[s][4] = (_Float16)u1.x; a[s][5] = (_Float16)u1.y;
                    a[s][6] = (_Float16)u1.z; a[s][7] = (_Float16)u1.w;
                }
            }
        } else {
            #pragma unroll
            for (int s = 0; s < 4; ++s) a[s] = (half8){};
        }
        floatx4 acc[8];
        #pragma unroll
        for (int g = 0; g < 8; ++g) {
            floatx4 c = zero4;
            #pragma unroll
            for (int s = 0; s < 4; ++s) {
                half8 b = *(const half8*)(sW + swz16(g * 16 + m, 4 * s + q));
                c = __builtin_amdgcn_mfma_f32_16x16x32_f16(a[s], b, c, 0, 0, 0);
            }
            acc[g] = c;
        }
        #pragma unroll
        for (int r = 0; r < 4; ++r) {
            const int grow = tile * 64 + w * 16 + q * 4 + r;
            if (grow < M) {
                TOUT* op = out + (size_t)grow * 128;
                #pragma unroll
                for (int g = 0; g < 8; ++g) {
                    float v = acc[g][r] + bv[g];
                    if (SSP_OUT) v = sspf(v);
                    op[g * 16 + m] = (TOUT)v;
                }
            }
        }
    }
}

// ---------------- fused output: out = ssp(agg@Wo1+bo1)@Wo2+bo2 (tmp stays on-chip) ----
__global__ __launch_bounds__(256) void out_kernel(
    const float* __restrict__ A, const _Float16* __restrict__ Wimg1,
    const _Float16* __restrict__ Wimg2, const float* __restrict__ bo1,
    const float* __restrict__ bo2, float* __restrict__ out, int M)
{
    __shared__ char sW[65536];                  // [0,32K)=Wo1 std, [32K,64K)=Wo2 col-perm
    __shared__ char sS[4][4096];                // wave-private 16-row slabs
    const int t = threadIdx.x;
    const int w = t >> 6, lane = t & 63, m = lane & 15, q = lane >> 4;

    stage_img<256>(Wimg1, sW, t);
    stage_img<256>(Wimg2, sW + 32768, t);
    float b1v[8];
    #pragma unroll
    for (int g = 0; g < 8; ++g) b1v[g] = bo1[g * 16 + m];
    float4 o2lo = *(const float4*)(bo2 + m * 8);
    float4 o2hi = *(const float4*)(bo2 + m * 8 + 4);
    float b2v[8] = {o2lo.x, o2lo.y, o2lo.z, o2lo.w, o2hi.x, o2hi.y, o2hi.z, o2hi.w};
    __syncthreads();

    char* mySS = sS[w];
    const floatx4 zero4 = {0.f, 0.f, 0.f, 0.f};
    const int ntiles = (M + 63) >> 6;
    for (int tile = blockIdx.x; tile < ntiles; tile += gridDim.x) {
        const int arow = tile * 64 + w * 16 + m;
        half8 a[4];
        if (arow < M) {
            const float* ap = A + (size_t)arow * 128;
            #pragma unroll
            for (int s = 0; s < 4; ++s) {
                float4 u0 = *(const float4*)(ap + s * 32 + q * 8);
                float4 u1 = *(const float4*)(ap + s * 32 + q * 8 + 4);
                a[s][0] = (_Float16)u0.x; a[s][1] = (_Float16)u0.y;
                a[s][2] = (_Float16)u0.z; a[s][3] = (_Float16)u0.w;
                a[s][4] = (_Float16)u1.x; a[s][5] = (_Float16)u1.y;
                a[s][6] = (_Float16)u1.z; a[s][7] = (_Float16)u1.w;
            }
        } else {
            #pragma unroll
            for (int s = 0; s < 4; ++s) a[s] = (half8){};
        }
        // stage 1: t = ssp(A@Wo1 + bo1), written to wave-private slab (std feature order)
        #pragma unroll
        for (int g = 0; g < 8; ++g) {
            floatx4 c = zero4;
            #pragma unroll
            for (int s = 0; s < 4; ++s) {
                half8 b = *(const half8*)(sW + swz16(g * 16 + m, 4 * s + q));
                c = __builtin_amdgcn_mfma_f32_16x16x32_f16(a[s], b, c, 0, 0, 0);
            }
            #pragma unroll
            for (int r = 0; r < 4; ++r) {
                float v = sspf(c[r] + b1v[g]);
                *(_Float16*)(mySS + swz16(q * 4 + r, 2 * g + (m >> 3)) + ((m & 7) << 1)) =
                    (_Float16)v;
            }
        }
        half8 a2[4];
        #pragma unroll
        for (int s = 0; s < 4; ++s)
            a2[s] = *(const half8*)(mySS + swz16(m, 4 * s + q));
        // stage 2: out = t@Wo2 + bo2 (Wo2 col-permuted -> lane m owns cols m*8..m*8+7)
        floatx4 acc[8];
        #pragma unroll
        for (int g = 0; g < 8; ++g) {
            floatx4 c = zero4;
            #pragma unroll
            for (int s = 0; s < 4; ++s) {
                half8 b = *(const half8*)(sW + 32768 + swz16(g * 16 + m, 4 * s + q));
                c = __builtin_amdgcn_mfma_f32_16x16x32_f16(a2[s], b, c, 0, 0, 0);
            }
            acc[g] = c;
        }
        #pragma unroll
        for (int r = 0; r < 4; ++r) {
            const int grow = tile * 64 + w * 16 + q * 4 + r;
            if (grow < M) {
                float* op = out + (size_t)grow * 128 + m * 8;
                float4 lo = {acc[0][r] + b2v[0], acc[1][r] + b2v[1],
                             acc[2][r] + b2v[2], acc[3][r] + b2v[3]};
                float4 hi = {acc[4][r] + b2v[4], acc[5][r] + b2v[5],
                             acc[6][r] + b2v[6], acc[7][r] + b2v[7]};
                *(float4*)op = lo;
                *(float4*)(op + 4) = hi;
            }
        }
    }
}

// ---------------- edge kernel (sorted+permuted, 48B records, perm features):
// lane m owns features m*8..m*8+7 -> h gathers are 4x half8; flush contiguous. ----
__global__ __launch_bounds__(256) void edge_kernel(
    const u64* __restrict__ f_s, const int* __restrict__ desc,
    const int* __restrict__ meta,
    const float* __restrict__ Wf1, const float* __restrict__ bf1,
    const _Float16* __restrict__ Wf2img, const float* __restrict__ bf2,
    const _Float16* __restrict__ h, float* __restrict__ agg)
{
    __shared__ char sW2[32768];
    __shared__ char sS[4][4096];   // wave-private 16-row slabs
    const int t = threadIdx.x;
    const int w = t >> 6, lane = t & 63, m = lane & 15, q = lane >> 4;

    stage_img<256>(Wf2img, sW2, t);
    half8 bW1[8];
    #pragma unroll
    for (int g = 0; g < 8; ++g) {
        #pragma unroll
        for (int j = 0; j < 8; ++j) {
            int k = q * 8 + j;
            bW1[g][j] = (k < NRBF) ? (_Float16)Wf1[k * 128 + m * 8 + g] : (_Float16)0.0f;
        }
    }
    float4 b1lo = *(const float4*)(bf1 + m * 8), b1hi = *(const float4*)(bf1 + m * 8 + 4);
    float4 b2lo = *(const float4*)(bf2 + m * 8), b2hi = *(const float4*)(bf2 + m * 8 + 4);
    float bf1r[8] = {b1lo.x, b1lo.y, b1lo.z, b1lo.w, b1hi.x, b1hi.y, b1hi.z, b1hi.w};
    float bf2r[8] = {b2lo.x, b2lo.y, b2lo.z, b2lo.w, b2hi.x, b2hi.y, b2hi.z, b2hi.w};
    __syncthreads();   // no barriers after this

    char* mySS = sS[w];
    const floatx4 zero4 = {0.f, 0.f, 0.f, 0.f};
    const int NT = meta[0];
    const int nw = gridDim.x * 4;
    const int wid = blockIdx.x * 4 + w;
    const int T = (NT + nw - 1) / nw;
    int t0 = wid * T, t1 = t0 + T;
    if (t1 > NT) t1 = NT;
    if (t0 >= t1) return;

    auto loadtile = [&](int tt, int& d_, u64& x0_, u64& x1_, u64* rcj) {
        d_ = desc[tt];
        const u64* base = f_s + (size_t)(tt * 16 + m) * 6;
        u64 x0 = 0, x1 = 0;
        if (q < 2)       { x0 = base[2 * q]; x1 = base[2 * q + 1]; }
        else if (q == 2) { x0 = base[4]; }
        x0_ = x0; x1_ = x1;
        const u64* rbase = f_s + (size_t)(tt * 16 + q * 4) * 6;
        rcj[0] = rbase[5];  rcj[1] = rbase[11];
        rcj[2] = rbase[17]; rcj[3] = rbase[23];
    };

    int d; u64 u0, u1; u64 rcj[4];
    loadtile(t0, d, u0, u1, rcj);

    float racc[8];
    #pragma unroll
    for (int g = 0; g < 8; ++g) racc[g] = 0.f;

    for (int tt = t0; tt < t1; ++tt) {
        const int nv = d & 31;
        const int atom = d >> 5;

        // unpack + mask per-slot meta (rows q*4+r)
        float rc[4]; int jm[4];
        #pragma unroll
        for (int r = 0; r < 4; ++r) {
            bool ok = (q * 4 + r) < nv;
            rc[r] = ok ? __uint_as_float((unsigned)rcj[r]) : 0.f;
            jm[r] = ok ? (int)((rcj[r] >> 32) & 0xffffu) : 0;
        }
        // h gathers: contiguous half8 per row (features m*8..m*8+7)
        half8 hv[4];
        #pragma unroll
        for (int r = 0; r < 4; ++r)
            hv[r] = *(const half8*)(h + (size_t)jm[r] * NF + m * 8);

        // prefetch next tile (sequential)
        int nd = 0; u64 nu0 = 0, nu1 = 0; u64 nrcj[4] = {0, 0, 0, 0};
        if (tt + 1 < t1) loadtile(tt + 1, nd, nu0, nu1, nrcj);

        // a1 from record (zero padded rows)
        union { u64 uu[2]; half8 v; } cv;
        cv.uu[0] = u0; cv.uu[1] = u1;
        half8 a1 = cv.v;
        if (m >= nv) a1 = (half8){};

        // mm1: s-feature (m*8+g) at slab col 16g+m
        floatx4 c1[8];
        #pragma unroll
        for (int g = 0; g < 8; ++g)
            c1[g] = __builtin_amdgcn_mfma_f32_16x16x32_f16(a1, bW1[g], zero4, 0, 0, 0);

        #pragma unroll
        for (int g = 0; g < 8; ++g) {
            #pragma unroll
            for (int r = 0; r < 4; ++r) {
                float v = sspf(c1[g][r] + bf1r[g]);
                *(_Float16*)(mySS + swz16(q * 4 + r, 2 * g + (m >> 3)) + ((m & 7) << 1)) =
                    (_Float16)v;
            }
        }
        half8 a2[4];
        #pragma unroll
        for (int s = 0; s < 4; ++s)
            a2[s] = *(const half8*)(mySS + swz16(m, 4 * s + q));

        // mm2 (row+col permuted Wf2 image) + fused accumulate
        #pragma unroll
        for (int g = 0; g < 8; ++g) {
            floatx4 c = zero4;
            #pragma unroll
            for (int s = 0; s < 4; ++s) {
                half8 b = *(const half8*)(sW2 + swz16(g * 16 + m, 4 * s + q));
                c = __builtin_amdgcn_mfma_f32_16x16x32_f16(a2[s], b, c, 0, 0, 0);
            }
            #pragma unroll
            for (int r = 0; r < 4; ++r)
                racc[g] += ((c[r] + bf2r[g]) * rc[r]) * (float)hv[r][g];
        }

        // flush when the atom run ends
        bool last = (tt + 1 >= t1);
        if (last || (nd >> 5) != atom) {
            float* arow = agg + (size_t)atom * NF + m * 8;
            #pragma unroll
            for (int g = 0; g < 8; ++g) {
                float v = racc[g];
                v += __shfl_xor(v, 16, 64);
                v += __shfl_xor(v, 32, 64);
                if (q == 0) atomicAdd(&arow[g], v);
                racc[g] = 0.f;
            }
        }
        d = nd; u0 = nu0; u1 = nu1;
        rcj[0] = nrcj[0]; rcj[1] = nrcj[1]; rcj[2] = nrcj[2]; rcj[3] = nrcj[3];
    }
}

// ---------------- fallback edge kernel (atomic-per-edge, perm-consistent) ----------------
__global__ __launch_bounds__(256) void edge_atomic_kernel(
    const float* __restrict__ f_ij, const float* __restrict__ rcut,
    const float* __restrict__ Wf1, const float* __restrict__ bf1,
    const _Float16* __restrict__ Wf2img, const float* __restrict__ bf2,
    const int* __restrict__ idx_i, const int* __restrict__ idx_j,
    const _Float16* __restrict__ h, float* __restrict__ agg)
{
    __shared__ char sW2[32768];
    __shared__ char sS[4][4096];
    const int NTILES = N_PAIRS / 64;
    const int t = threadIdx.x;
    const int w = t >> 6, lane = t & 63, m = lane & 15, q = lane >> 4;

    stage_img<256>(Wf2img, sW2, t);
    half8 bW1[8];
    #pragma unroll
    for (int g = 0; g < 8; ++g) {
        #pragma unroll
        for (int j = 0; j < 8; ++j) {
            int k = q * 8 + j;
            bW1[g][j] = (k < NRBF) ? (_Float16)Wf1[k * 128 + m * 8 + g] : (_Float16)0.0f;
        }
    }
    float4 b1lo = *(const float4*)(bf1 + m * 8), b1hi = *(const float4*)(bf1 + m * 8 + 4);
    float4 b2lo = *(const float4*)(bf2 + m * 8), b2hi = *(const float4*)(bf2 + m * 8 + 4);
    float bf1r[8] = {b1lo.x, b1lo.y, b1lo.z, b1lo.w, b1hi.x, b1hi.y, b1hi.z, b1hi.w};
    float bf2r[8] = {b2lo.x, b2lo.y, b2lo.z, b2lo.w, b2hi.x, b2hi.y, b2hi.z, b2hi.w};
    __syncthreads();

    char* mySS = sS[w];
    const floatx4 zero4 = {0.f, 0.f, 0.f, 0.f};
    const float4 fz = {0.f, 0.f, 0.f, 0.f};

    for (int tile = blockIdx.x; tile < NTILES; tile += gridDim.x) {
        const int e0 = tile * 64 + w * 16;
        float4 f0 = fz, f1 = fz;
        const float* fb = f_ij + (size_t)(e0 + m) * NRBF + q * 8;
        if (q < 2)      { f0 = *(const float4*)fb; f1 = *(const float4*)(fb + 4); }
        else if (q == 2){ f0 = *(const float4*)fb; }
        int4 jj4 = *(const int4*)&idx_j[e0 + q * 4];
        int4 ii4 = *(const int4*)&idx_i[e0 + q * 4];
        float4 rc4 = *(const float4*)&rcut[e0 + q * 4];
        int jj[4] = {jj4.x, jj4.y, jj4.z, jj4.w};
        half8 hv[4];
        #pragma unroll
        for (int r = 0; r < 4; ++r)
            hv[r] = *(const half8*)(h + (size_t)jj[r] * NF + m * 8);

        half8 a1;
        a1[0]=(_Float16)f0.x; a1[1]=(_Float16)f0.y; a1[2]=(_Float16)f0.z; a1[3]=(_Float16)f0.w;
        a1[4]=(_Float16)f1.x; a1[5]=(_Float16)f1.y; a1[6]=(_Float16)f1.z; a1[7]=(_Float16)f1.w;
        floatx4 c1[8];
        #pragma unroll
        for (int g = 0; g < 8; ++g)
            c1[g] = __builtin_amdgcn_mfma_f32_16x16x32_f16(a1, bW1[g], zero4, 0, 0, 0);

        #pragma unroll
        for (int g = 0; g < 8; ++g) {
            #pragma unroll
            for (int r = 0; r < 4; ++r) {
                float v = sspf(c1[g][r] + bf1r[g]);
                *(_Float16*)(mySS + swz16(q * 4 + r, 2 * g + (m >> 3)) + ((m & 7) << 1)) =
                    (_Float16)v;
            }
        }
        half8 a2[4];
        #pragma unroll
        for (int s = 0; s < 4; ++s)
            a2[s] = *(const half8*)(mySS + swz16(m, 4 * s + q));

        floatx4 acc[8];
        #pragma unroll
        for (int g = 0; g < 8; ++g) {
            floatx4 c = zero4;
            #pragma unroll
            for (int s = 0; s < 4; ++s) {
                half8 b = *(const half8*)(sW2 + swz16(g * 16 + m, 4 * s + q));
                c = __builtin_amdgcn_mfma_f32_16x16x32_f16(a2[s], b, c, 0, 0, 0);
            }
            acc[g] = c;
        }
        int ii[4] = {ii4.x, ii4.y, ii4.z, ii4.w};
        float rc[4] = {rc4.x, rc4.y, rc4.z, rc4.w};
        #pragma unroll
        for (int r = 0; r < 4; ++r) {
            float* arow = agg + (size_t)ii[r] * 128 + m * 8;
            #pragma unroll
            for (int g = 0; g < 8; ++g) {
                float wij = (acc[g][r] + bf2r[g]) * rc[r];
                atomicAdd(&arow[g], (float)hv[r][g] * wij);
            }
        }
    }
}

extern "C" void kernel_launch(void* const* d_in, const int* in_sizes, int n_in,
                              void* d_out, int out_size, void* d_ws, size_t ws_size,
                              hipStream_t stream) {
    const float* x     = (const float*)d_in[0];
    const float* f_ij  = (const float*)d_in[1];
    const float* rcutp = (const float*)d_in[2];
    const float* W_in  = (const float*)d_in[3];
    const float* b_in  = (const float*)d_in[4];
    const float* Wf1   = (const float*)d_in[5];
    const float* bf1   = (const float*)d_in[6];
    const float* Wf2   = (const float*)d_in[7];
    const float* bf2   = (const float*)d_in[8];
    const float* Wo1   = (const float*)d_in[9];
    const float* bo1   = (const float*)d_in[10];
    const float* Wo2   = (const float*)d_in[11];
    const float* bo2   = (const float*)d_in[12];
    const int* idx_i   = (const int*)d_in[13];
    const int* idx_j   = (const int*)d_in[14];
    float* out = (float*)d_out;

    // workspace layout (16B-aligned offsets)
    char* ws = (char*)d_ws;
    float*     agg   = (float*)ws;                       // 25,600,000
    _Float16*  h     = (_Float16*)(ws + 25600000);       // 12,800,000
    _Float16*  Wimg  = (_Float16*)(ws + 38400000);       //    131,072
    int*       woffs = (int*)(ws + 38531072);            //    200,000
    int*       meta  = (int*)(ws + 38731072);            //         16
    int*       bsum  = (int*)(ws + 38731088);            //        784 -> pad 800
    int*       bpre  = (int*)(ws + 38731888);            //        784 -> pad 800
    int*       desc  = (int*)(ws + 38732688);            //    512,500 -> pad 512,512
    u64*       f_s   = (u64*)(ws + 39245200);            // 98,400,000 (2.05M x 48B)
    const size_t NEED = 137645200;

    const int zc4 = N_ATOMS * NF / 4;
    prep_kernel<<<dim3(4), 256, 0, stream>>>(W_in, Wf2, Wo1, Wo2, Wimg, woffs);

    if (ws_size >= NEED) {
        // gemm1 with fused agg-zero and fused histogram
        gemm_mfma_kernel<float, _Float16, false, true, true>
            <<<dim3(782), 256, 0, stream>>>(x, Wimg, b_in, h, N_ATOMS, agg, zc4,
                                            idx_i, woffs);
        scanA_kernel<<<dim3(NBLK), 256, 0, stream>>>(woffs, bsum);
        scanB_kernel<<<dim3(1), 256, 0, stream>>>(bsum, bpre, meta);
        scanC_kernel<<<dim3(NBLK), 256, 0, stream>>>(woffs, bpre, desc);
        scatter_kernel<<<dim3(1024), 256, 0, stream>>>(
            f_ij, rcutp, idx_i, idx_j, woffs, f_s);
        edge_kernel<<<dim3(768), 256, 0, stream>>>(
            f_s, desc, meta, Wf1, bf1, Wimg + 16384, bf2, h, agg);
    } else {
        gemm_mfma_kernel<float, _Float16, false, true, false>
            <<<dim3(782), 256, 0, stream>>>(x, Wimg, b_in, h, N_ATOMS, agg, zc4,
                                            nullptr, nullptr);
        edge_atomic_kernel<<<dim3(768), 256, 0, stream>>>(
            f_ij, rcutp, Wf1, bf1, Wimg + 16384, bf2, idx_i, idx_j, h, agg);
    }

    // fused: out = ssp(agg@Wo1+bo1)@Wo2+bo2 (no tmp round-trip)
    out_kernel<<<dim3(782), 256, 0, stream>>>(
        agg, Wimg + 32768, Wimg + 49152, bo1, bo2, out, N_ATOMS);
}